// Round 4
// baseline (167.327 us; speedup 1.0000x reference)
//
#include <hip/hip_runtime.h>

#define MAXT 16
#define DDIM 1024
#define NTHREADS 256
#define TPW 4          // depths per wave (4 waves x 4 = 16 = MAXT)

__global__ __launch_bounds__(NTHREADS, 3)
void attn_depth_kernel(const float* __restrict__ entries,
                       const float* __restrict__ proj,
                       const float* __restrict__ norm_scale,
                       const int* __restrict__ n_active_p,
                       const int* __restrict__ block_idx_p,
                       float* __restrict__ out,
                       int BS)
{
    const int site = blockIdx.x;          // b*S + s
    const int tid  = threadIdx.x;
    const int wave = tid >> 6;
    const int lane = tid & 63;

    int n_act = *n_active_p;
    n_act = n_act < 1 ? 1 : (n_act > MAXT ? MAXT : n_act);
    int row = *block_idx_p;
    row = row > (MAXT - 1) ? (MAXT - 1) : (row < 0 ? 0 : row);

    // This thread's d-elements: d(c,j) = c*256 + lane*4 + j, c = 0..3
    const int dbase = lane * 4;

    const size_t tStride = (size_t)BS * DDIM;
    const float* ebase = entries + (size_t)site * DDIM + dbase;

    // INTERLEAVED depth ownership: wave w owns t = w + 4*tt.
    // With n_act=12 every wave loads exactly 3 slices (balanced VMEM critical
    // path), vs 4/4/4/0 for the blocked assignment.
    float4 e[TPW][4];
#pragma unroll
    for (int tt = 0; tt < TPW; ++tt) {
        const int t = wave + 4 * tt;            // wave-uniform
        if (t < n_act) {
#pragma unroll
            for (int c = 0; c < 4; ++c)
                e[tt][c] = *reinterpret_cast<const float4*>(ebase + (size_t)t * tStride + c * 256);
        } else {
#pragma unroll
            for (int c = 0; c < 4; ++c)
                e[tt][c] = make_float4(0.f, 0.f, 0.f, 0.f);
        }
    }

    // q = proj[row] * norm_scale at this thread's d-elements (cached, tiny)
    float4 q[4];
#pragma unroll
    for (int c = 0; c < 4; ++c) {
        float4 p  = *reinterpret_cast<const float4*>(proj + (size_t)row * DDIM + c * 256 + dbase);
        float4 ns = *reinterpret_cast<const float4*>(norm_scale + c * 256 + dbase);
        q[c] = make_float4(p.x * ns.x, p.y * ns.y, p.z * ns.z, p.w * ns.w);
    }

    // Per-depth partials over this thread's 16 elements
    float ss[TPW], dt[TPW];
#pragma unroll
    for (int tt = 0; tt < TPW; ++tt) {
        float s = 0.f, d = 0.f;
#pragma unroll
        for (int c = 0; c < 4; ++c) {
            const float4 v = e[tt][c];
            s = fmaf(v.x, v.x, s); s = fmaf(v.y, v.y, s);
            s = fmaf(v.z, v.z, s); s = fmaf(v.w, v.w, s);
            d = fmaf(q[c].x, v.x, d); d = fmaf(q[c].y, v.y, d);
            d = fmaf(q[c].z, v.z, d); d = fmaf(q[c].w, v.w, d);
        }
        ss[tt] = s; dt[tt] = d;
    }

    // 64-lane butterfly; 8 independent chains (4 depths x 2 values) for ILP.
#pragma unroll
    for (int off = 32; off >= 1; off >>= 1) {
#pragma unroll
        for (int tt = 0; tt < TPW; ++tt) {
            ss[tt] += __shfl_xor(ss[tt], off, 64);
            dt[tt] += __shfl_xor(dt[tt], off, 64);
        }
    }

    __shared__ float red[2 * MAXT];        // [0..15]=ss, [16..31]=dt (by t)
    __shared__ float part[TPW][DDIM];      // per-wave partial outputs (16 KB)

    if (lane == 0) {
#pragma unroll
        for (int tt = 0; tt < TPW; ++tt) {
            const int t = wave + 4 * tt;
            red[t]        = ss[tt];
            red[MAXT + t] = dt[tt];
        }
    }
    __syncthreads();

    // Redundant per-thread softmax stats (m, sum) over all 16 depths.
    float lg[MAXT];
    float4 rs[4], rd[4];
#pragma unroll
    for (int c = 0; c < 4; ++c) {
        rs[c] = *reinterpret_cast<const float4*>(&red[c * 4]);
        rd[c] = *reinterpret_cast<const float4*>(&red[MAXT + c * 4]);
    }
#pragma unroll
    for (int c = 0; c < 4; ++c) {
        lg[c * 4 + 0] = rd[c].x * rsqrtf(rs[c].x * (1.f / DDIM) + 1e-5f);
        lg[c * 4 + 1] = rd[c].y * rsqrtf(rs[c].y * (1.f / DDIM) + 1e-5f);
        lg[c * 4 + 2] = rd[c].z * rsqrtf(rs[c].z * (1.f / DDIM) + 1e-5f);
        lg[c * 4 + 3] = rd[c].w * rsqrtf(rs[c].w * (1.f / DDIM) + 1e-5f);
    }
    float m = -3.0e38f;
#pragma unroll
    for (int t = 0; t < MAXT; ++t)
        if (t < n_act) m = fmaxf(m, lg[t]);
    float sum = 0.f;
#pragma unroll
    for (int t = 0; t < MAXT; ++t)
        if (t < n_act) sum += __expf(lg[t] - m);
    const float inv = 1.f / sum;

    // This wave's 4 weights, recomputed from LDS at runtime ADDRESS only.
    float wt[TPW];
#pragma unroll
    for (int tt = 0; tt < TPW; ++tt) {
        const int t = wave + 4 * tt;
        const float s_ = red[t];
        const float d_ = red[MAXT + t];
        const float l_ = d_ * rsqrtf(s_ * (1.f / DDIM) + 1e-5f);
        wt[tt] = (t < n_act) ? __expf(l_ - m) * inv : 0.f;
    }

    // Weighted partial over this wave's depths (masked t: wt==0 and e==0).
    float4 acc[4];
#pragma unroll
    for (int c = 0; c < 4; ++c) acc[c] = make_float4(0.f, 0.f, 0.f, 0.f);
#pragma unroll
    for (int tt = 0; tt < TPW; ++tt) {
#pragma unroll
        for (int c = 0; c < 4; ++c) {
            acc[c].x = fmaf(wt[tt], e[tt][c].x, acc[c].x);
            acc[c].y = fmaf(wt[tt], e[tt][c].y, acc[c].y);
            acc[c].z = fmaf(wt[tt], e[tt][c].z, acc[c].z);
            acc[c].w = fmaf(wt[tt], e[tt][c].w, acc[c].w);
        }
    }
#pragma unroll
    for (int c = 0; c < 4; ++c)
        *reinterpret_cast<float4*>(&part[wave][c * 256 + dbase]) = acc[c];
    __syncthreads();

    // Cross-wave combine: thread owns out[tid*4 .. tid*4+3].
    const int od = tid * 4;
    float4 r0 = *reinterpret_cast<const float4*>(&part[0][od]);
    float4 r1 = *reinterpret_cast<const float4*>(&part[1][od]);
    float4 r2 = *reinterpret_cast<const float4*>(&part[2][od]);
    float4 r3 = *reinterpret_cast<const float4*>(&part[3][od]);
    float4 r;
    r.x = (r0.x + r1.x) + (r2.x + r3.x);
    r.y = (r0.y + r1.y) + (r2.y + r3.y);
    r.z = (r0.z + r1.z) + (r2.z + r3.z);
    r.w = (r0.w + r1.w) + (r2.w + r3.w);
    *reinterpret_cast<float4*>(out + (size_t)site * DDIM + od) = r;
}

extern "C" void kernel_launch(void* const* d_in, const int* in_sizes, int n_in,
                              void* d_out, int out_size, void* d_ws, size_t ws_size,
                              hipStream_t stream)
{
    const float* entries = (const float*)d_in[0];
    const float* proj    = (const float*)d_in[1];
    const float* nscale  = (const float*)d_in[2];
    const int*   n_act   = (const int*)d_in[3];
    const int*   bidx    = (const int*)d_in[4];
    float*       out     = (float*)d_out;

    const int BS = out_size / DDIM;   // B*S = 16384
    attn_depth_kernel<<<BS, NTHREADS, 0, stream>>>(entries, proj, nscale,
                                                   n_act, bidx, out, BS);
}

// Round 5
// 162.374 us; speedup vs baseline: 1.0305x; 1.0305x over previous
//
#include <hip/hip_runtime.h>

#define MAXT 16
#define DDIM 1024
#define NTHREADS 256
#define TPW 4          // depths per wave (4 waves x 4 = 16 = MAXT)

// Full wave64 sum via DPP (VALU pipe only, no DS ops).
// Canonical AMD sequence: row_shr 1/2/4/8 (prefix within 16-lane rows),
// row_bcast15 into rows 1,3 and row_bcast31 into rows 2,3.
// Total lands in lane 63; readlane broadcasts it to all lanes (SGPR).
__device__ __forceinline__ float dpp_sum64(float x) {
    int v;
    v = __builtin_amdgcn_update_dpp(0, __float_as_int(x), 0x111, 0xf, 0xf, true);  // row_shr:1
    x += __int_as_float(v);
    v = __builtin_amdgcn_update_dpp(0, __float_as_int(x), 0x112, 0xf, 0xf, true);  // row_shr:2
    x += __int_as_float(v);
    v = __builtin_amdgcn_update_dpp(0, __float_as_int(x), 0x114, 0xf, 0xf, true);  // row_shr:4
    x += __int_as_float(v);
    v = __builtin_amdgcn_update_dpp(0, __float_as_int(x), 0x118, 0xf, 0xf, true);  // row_shr:8
    x += __int_as_float(v);
    v = __builtin_amdgcn_update_dpp(0, __float_as_int(x), 0x142, 0xa, 0xf, false); // row_bcast:15 -> rows 1,3
    x += __int_as_float(v);
    v = __builtin_amdgcn_update_dpp(0, __float_as_int(x), 0x143, 0xc, 0xf, false); // row_bcast:31 -> rows 2,3
    x += __int_as_float(v);
    return __int_as_float(__builtin_amdgcn_readlane(__float_as_int(x), 63));
}

__global__ __launch_bounds__(NTHREADS, 3)
void attn_depth_kernel(const float* __restrict__ entries,
                       const float* __restrict__ proj,
                       const float* __restrict__ norm_scale,
                       const int* __restrict__ n_active_p,
                       const int* __restrict__ block_idx_p,
                       float* __restrict__ out,
                       int BS)
{
    const int site = blockIdx.x;          // b*S + s
    const int tid  = threadIdx.x;
    const int wave = tid >> 6;
    const int lane = tid & 63;

    int n_act = *n_active_p;
    n_act = n_act < 1 ? 1 : (n_act > MAXT ? MAXT : n_act);
    int row = *block_idx_p;
    row = row > (MAXT - 1) ? (MAXT - 1) : (row < 0 ? 0 : row);

    // This thread's d-elements: d(c,j) = c*256 + lane*4 + j, c = 0..3
    const int dbase = lane * 4;

    const size_t tStride = (size_t)BS * DDIM;
    const float* ebase = entries + (size_t)site * DDIM + dbase;

    // Interleaved depth ownership: wave w owns t = w + 4*tt (balanced loads).
    float4 e[TPW][4];
#pragma unroll
    for (int tt = 0; tt < TPW; ++tt) {
        const int t = wave + 4 * tt;            // wave-uniform
        if (t < n_act) {
#pragma unroll
            for (int c = 0; c < 4; ++c)
                e[tt][c] = *reinterpret_cast<const float4*>(ebase + (size_t)t * tStride + c * 256);
        } else {
#pragma unroll
            for (int c = 0; c < 4; ++c)
                e[tt][c] = make_float4(0.f, 0.f, 0.f, 0.f);
        }
    }

    // q = proj[row] * norm_scale at this thread's d-elements (cached, tiny)
    float4 q[4];
#pragma unroll
    for (int c = 0; c < 4; ++c) {
        float4 p  = *reinterpret_cast<const float4*>(proj + (size_t)row * DDIM + c * 256 + dbase);
        float4 ns = *reinterpret_cast<const float4*>(norm_scale + c * 256 + dbase);
        q[c] = make_float4(p.x * ns.x, p.y * ns.y, p.z * ns.z, p.w * ns.w);
    }

    // Per-depth partials over this thread's 16 elements
    float ss[TPW], dt[TPW];
#pragma unroll
    for (int tt = 0; tt < TPW; ++tt) {
        float s = 0.f, d = 0.f;
#pragma unroll
        for (int c = 0; c < 4; ++c) {
            const float4 v = e[tt][c];
            s = fmaf(v.x, v.x, s); s = fmaf(v.y, v.y, s);
            s = fmaf(v.z, v.z, s); s = fmaf(v.w, v.w, s);
            d = fmaf(q[c].x, v.x, d); d = fmaf(q[c].y, v.y, d);
            d = fmaf(q[c].z, v.z, d); d = fmaf(q[c].w, v.w, d);
        }
        ss[tt] = s; dt[tt] = d;
    }

    // Wave64 reduction on the VALU pipe (DPP) — no DS ops, short dep chains.
#pragma unroll
    for (int tt = 0; tt < TPW; ++tt) {
        ss[tt] = dpp_sum64(ss[tt]);
        dt[tt] = dpp_sum64(dt[tt]);
    }

    __shared__ float red[2 * MAXT];        // [0..15]=ss, [16..31]=dt (by t)
    __shared__ float part[TPW][DDIM];      // per-wave partial outputs (16 KB)

    if (lane == 0) {
#pragma unroll
        for (int tt = 0; tt < TPW; ++tt) {
            const int t = wave + 4 * tt;
            red[t]        = ss[tt];
            red[MAXT + t] = dt[tt];
        }
    }
    __syncthreads();

    // Redundant per-thread softmax stats (m, sum) over all 16 depths.
    float lg[MAXT];
    float4 rs[4], rd[4];
#pragma unroll
    for (int c = 0; c < 4; ++c) {
        rs[c] = *reinterpret_cast<const float4*>(&red[c * 4]);
        rd[c] = *reinterpret_cast<const float4*>(&red[MAXT + c * 4]);
    }
#pragma unroll
    for (int c = 0; c < 4; ++c) {
        lg[c * 4 + 0] = rd[c].x * rsqrtf(rs[c].x * (1.f / DDIM) + 1e-5f);
        lg[c * 4 + 1] = rd[c].y * rsqrtf(rs[c].y * (1.f / DDIM) + 1e-5f);
        lg[c * 4 + 2] = rd[c].z * rsqrtf(rs[c].z * (1.f / DDIM) + 1e-5f);
        lg[c * 4 + 3] = rd[c].w * rsqrtf(rs[c].w * (1.f / DDIM) + 1e-5f);
    }
    float m = -3.0e38f;
#pragma unroll
    for (int t = 0; t < MAXT; ++t)
        if (t < n_act) m = fmaxf(m, lg[t]);
    float sum = 0.f;
#pragma unroll
    for (int t = 0; t < MAXT; ++t)
        if (t < n_act) sum += __expf(lg[t] - m);
    const float inv = 1.f / sum;

    // This wave's 4 weights, recomputed from LDS at runtime ADDRESS only.
    float wt[TPW];
#pragma unroll
    for (int tt = 0; tt < TPW; ++tt) {
        const int t = wave + 4 * tt;
        const float s_ = red[t];
        const float d_ = red[MAXT + t];
        const float l_ = d_ * rsqrtf(s_ * (1.f / DDIM) + 1e-5f);
        wt[tt] = (t < n_act) ? __expf(l_ - m) * inv : 0.f;
    }

    // Weighted partial over this wave's depths (masked t: wt==0 and e==0).
    float4 acc[4];
#pragma unroll
    for (int c = 0; c < 4; ++c) acc[c] = make_float4(0.f, 0.f, 0.f, 0.f);
#pragma unroll
    for (int tt = 0; tt < TPW; ++tt) {
#pragma unroll
        for (int c = 0; c < 4; ++c) {
            acc[c].x = fmaf(wt[tt], e[tt][c].x, acc[c].x);
            acc[c].y = fmaf(wt[tt], e[tt][c].y, acc[c].y);
            acc[c].z = fmaf(wt[tt], e[tt][c].z, acc[c].z);
            acc[c].w = fmaf(wt[tt], e[tt][c].w, acc[c].w);
        }
    }
#pragma unroll
    for (int c = 0; c < 4; ++c)
        *reinterpret_cast<float4*>(&part[wave][c * 256 + dbase]) = acc[c];
    __syncthreads();

    // Cross-wave combine: thread owns out[tid*4 .. tid*4+3].
    const int od = tid * 4;
    float4 r0 = *reinterpret_cast<const float4*>(&part[0][od]);
    float4 r1 = *reinterpret_cast<const float4*>(&part[1][od]);
    float4 r2 = *reinterpret_cast<const float4*>(&part[2][od]);
    float4 r3 = *reinterpret_cast<const float4*>(&part[3][od]);
    float4 r;
    r.x = (r0.x + r1.x) + (r2.x + r3.x);
    r.y = (r0.y + r1.y) + (r2.y + r3.y);
    r.z = (r0.z + r1.z) + (r2.z + r3.z);
    r.w = (r0.w + r1.w) + (r2.w + r3.w);
    *reinterpret_cast<float4*>(out + (size_t)site * DDIM + od) = r;
}

extern "C" void kernel_launch(void* const* d_in, const int* in_sizes, int n_in,
                              void* d_out, int out_size, void* d_ws, size_t ws_size,
                              hipStream_t stream)
{
    const float* entries = (const float*)d_in[0];
    const float* proj    = (const float*)d_in[1];
    const float* nscale  = (const float*)d_in[2];
    const int*   n_act   = (const int*)d_in[3];
    const int*   bidx    = (const int*)d_in[4];
    float*       out     = (float*)d_out;

    const int BS = out_size / DDIM;   // B*S = 16384
    attn_depth_kernel<<<BS, NTHREADS, 0, stream>>>(entries, proj, nscale,
                                                   n_act, bidx, out, BS);
}